// Round 6
// baseline (453.327 us; speedup 1.0000x reference)
//
#include <hip/hip_runtime.h>
#include <hip/hip_bf16.h>

typedef __bf16 bf16_t;
typedef __attribute__((ext_vector_type(8))) __bf16 bf16x8;
typedef __attribute__((ext_vector_type(4))) float f32x4;

#define S_DIM 4096
#define D_DIM 2048

__device__ __forceinline__ unsigned short f2bf(float f) {
  unsigned int u = __float_as_uint(f);
  u += 0x7fff + ((u >> 16) & 1);   // round-to-nearest-even
  return (unsigned short)(u >> 16);
}
__device__ __forceinline__ float bf2f(unsigned short h) {
  return __uint_as_float(((unsigned int)h) << 16);
}

// async global->LDS, 16B per lane. LDS dest must be wave-uniform base + lane*16.
__device__ __forceinline__ void async16(const void* g, void* l) {
  __builtin_amdgcn_global_load_lds(
      (const __attribute__((address_space(1))) void*)g,
      (__attribute__((address_space(3))) void*)l, 16, 0, 0);
}

// ---------------------------------------------------------------------------
// init: zero rowsum[4096]; block 0 also runs the dtype probe.
__global__ void k_init(const unsigned int* __restrict__ x, int* __restrict__ flag,
                       float* __restrict__ rowsum) {
  const int idx = blockIdx.x * 256 + threadIdx.x;
  if (idx < S_DIM) rowsum[idx] = 0.f;
  if (blockIdx.x == 0) {
    __shared__ int cnt;
    if (threadIdx.x == 0) cnt = 0;
    __syncthreads();
    const unsigned int e = (x[threadIdx.x] >> 7) & 0xffu;
    if (e >= 100 && e <= 140) atomicAdd(&cnt, 1);
    __syncthreads();
    if (threadIdx.x == 0) *flag = (cnt > 128) ? 1 : 0;
  }
}

// convert (or copy) input to bf16; 4 elements per thread
__global__ void k_tobf16(const void* __restrict__ src, unsigned short* __restrict__ dst,
                         int n4, const int* __restrict__ flag) {
  int i = blockIdx.x * 256 + threadIdx.x;
  if (i >= n4) return;
  if (*flag) {
    ((uint2*)dst)[i] = ((const uint2*)src)[i];
  } else {
    float4 f = ((const float4*)src)[i];
    ushort4 u;
    u.x = f2bf(f.x); u.y = f2bf(f.y); u.z = f2bf(f.z); u.w = f2bf(f.w);
    ((ushort4*)dst)[i] = u;
  }
}

// all three weight matrices in one launch; i in [0, 3*2048*2048/4)
__global__ void k_tobf16w(const void* __restrict__ s0, const void* __restrict__ s1,
                          const void* __restrict__ s2, unsigned short* __restrict__ dst,
                          const int* __restrict__ flag) {
  const int i = blockIdx.x * 256 + threadIdx.x;      // 3 * 1048576 total
  const int which = i >> 20;
  const int off = i & 0xFFFFF;
  const void* src = (which == 0) ? s0 : ((which == 1) ? s1 : s2);
  if (*flag) {
    ((uint2*)dst)[i] = ((const uint2*)src)[off];
  } else {
    float4 f = ((const float4*)src)[off];
    ushort4 u;
    u.x = f2bf(f.x); u.y = f2bf(f.y); u.z = f2bf(f.z); u.w = f2bf(f.w);
    ((ushort4*)dst)[i] = u;
  }
}

// ===========================================================================
// m97-lite 2-barrier GEMM (PROVEN 105us / MfmaUtil 43% for qkv). 128x128 tile,
// 256 thr, waves 2x2, BK=64 as two BK=32 sub-tiles, 32KB LDS, 4 blocks/CU.
// JOURNAL: qkv8 deep-pipeline with BN=128 REGRESSED (118us, MfmaUtil 36.6%):
// 10 ds_read : 16 MFMA per phase is LDS-read-bound + per-phase vmcnt stalls.
// Swizzle itself verified (bank conflicts 1.26e7 -> 0). qkv stays here.
// R4: container infra failure. R5: compile error (const rowsum) — fixed.
__global__ __launch_bounds__(256, 4)
void k_gemm_qkv(const bf16_t* __restrict__ A, const bf16_t* __restrict__ B,
                unsigned short* __restrict__ C, int ldA, int ldB, int ldC, int K) {
  const int bm = blockIdx.y, bn = blockIdx.x;
  const int rowBase = bm * 128;

  __shared__ alignas(16) bf16_t As0[128 * 32];
  __shared__ alignas(16) bf16_t As1[128 * 32];
  __shared__ alignas(16) bf16_t Bs0[128 * 32];
  __shared__ alignas(16) bf16_t Bs1[128 * 32];

  const int tid = threadIdx.x;
  const int lane = tid & 63, wave = tid >> 6;
  const int quad = lane >> 4, l16 = lane & 15;
  const int wm = (wave >> 1) * 64;
  const int wn = (wave & 1) * 64;
  const int sr = tid >> 2;
  const int sc = (tid & 3) * 8;

  f32x4 acc[4][4] = {};

  const unsigned aOff = (unsigned)(rowBase + sr) * (unsigned)ldA + sc;
  const unsigned bOff = (unsigned)(bn * 128 + sr) * (unsigned)ldB + sc;
  const unsigned aOff2 = aOff + 64u * (unsigned)ldA;
  const unsigned bOff2 = bOff + 64u * (unsigned)ldB;
  const unsigned lOff = sr * 32 + sc;

  for (int k0 = 0; k0 < K; k0 += 64) {
    async16(A + (aOff + k0), &As0[lOff]);
    async16(A + (aOff + k0 + 32), &As1[lOff]);
    async16(A + (aOff2 + k0), &As0[lOff + 64 * 32]);
    async16(A + (aOff2 + k0 + 32), &As1[lOff + 64 * 32]);
    async16(B + (bOff + k0), &Bs0[lOff]);
    async16(B + (bOff2 + k0), &Bs0[lOff + 64 * 32]);
    async16(B + (bOff + k0 + 32), &Bs1[lOff]);
    async16(B + (bOff2 + k0 + 32), &Bs1[lOff + 64 * 32]);
    __syncthreads();

    bf16x8 b0[4], b1[4];
#pragma unroll
    for (int j = 0; j < 4; ++j) {
      b0[j] = *(const bf16x8*)&Bs0[(wn + j * 16 + l16) * 32 + quad * 8];
      b1[j] = *(const bf16x8*)&Bs1[(wn + j * 16 + l16) * 32 + quad * 8];
    }
#pragma unroll
    for (int i = 0; i < 4; ++i) {
      const bf16x8 a0 = *(const bf16x8*)&As0[(wm + i * 16 + l16) * 32 + quad * 8];
      const bf16x8 a1 = *(const bf16x8*)&As1[(wm + i * 16 + l16) * 32 + quad * 8];
#pragma unroll
      for (int j = 0; j < 4; ++j) {
        acc[i][j] = __builtin_amdgcn_mfma_f32_16x16x32_bf16(a0, b0[j], acc[i][j], 0, 0, 0);
        acc[i][j] = __builtin_amdgcn_mfma_f32_16x16x32_bf16(a1, b1[j], acc[i][j], 0, 0, 0);
      }
    }
    __syncthreads();
  }

#pragma unroll
  for (int i = 0; i < 4; ++i) {
    const int gr0 = rowBase + wm + i * 16 + quad * 4;
#pragma unroll
    for (int j = 0; j < 4; ++j) {
      const int gc = bn * 128 + wn + j * 16 + l16;
#pragma unroll
      for (int r = 0; r < 4; ++r)
        C[(size_t)(gr0 + r) * ldC + gc] = f2bf(acc[i][j][r]);
    }
  }
}

// ===========================================================================
// Faithful m201-style 4-phase pipelined GEMM for sc/av.
// BM=128, BN=256, BK=64. 512 thr = 8 waves (2Mx4N), per-wave 64x64 out,
// acc[4][4] f32x4 = 64 VGPR. LDS 96KB: A[2buf][2kh][128][32],
// B[2buf][2kh][256][32]. Per K-tile per wave: 16 ds_read_b128 : 32 MFMA.
//
// Phases = C-quadrants (ih,jh): p1(0,0) reads A0+B0 frags; p2(0,1) reads B1;
// p3(1,0) reads A1 (B0 held in regs); p4(1,1) no reads (A1,B1 held).
// Staging stagger-2 (each region staged >=1 barrier AFTER its last LDS read):
//   p1: A1(T+1)->buf^1   [last read: T-1.p3]
//   p2: B1(T+1)->buf^1   [last read: T-1.p2/p4]
//   p3: A0(T+2)->buf     [last read: T.p1]
//   p4: B0(T+2)->buf     [last read: T.p1]
// vmcnt ONCE per K-tile at p4: newest allowed in flight = A0+B0(T+2) = 3 loads
// -> vmcnt(3) guarantees all of tile T+1 resident. TAIL-EXACT: when T+2>=NT
// those stages vanish, so vmcnt(3) would no longer cover A1/B1(T+1) ->
// use vmcnt(0) at T=NT-2 (hand-traced on NT=2).
// Swizzle: source kslot ^= (tid>>3)&3 pre-applied to GLOBAL addr (LDS dest
// linear, rule #21); read side quad^((l16>>1)&3). Verified 0 conflicts (r3).
// OUT_MODE 3 = scores (exp*mask + rowsum atomics), 2 = av (/rowsum).
template<int OUT_MODE>
__device__ __forceinline__ void gemm8_body(
    const bf16_t* __restrict__ A, const bf16_t* __restrict__ B,
    void* __restrict__ C, int ldA, int ldB, int ldC,
    int bm, int bn, int NT, float scale,
    const int* __restrict__ flag, const void* __restrict__ mask,
    float* __restrict__ rowsum, bf16_t* sm) {
  const int tid = threadIdx.x;
  const int lane = tid & 63, wave = tid >> 6;
  const int quad = lane >> 4, l16 = lane & 15;
  const int wr = wave >> 2;            // 0..1 (64-row band)
  const int wc = wave & 3;             // 0..3 (64-col band)
  const int swq = (l16 >> 1) & 3;      // read-side swizzle

  // staging: A-half (64 rows x 64K) = 1 load/thread; B-half (128 x 64K) = 2.
  const int sA_kh = tid >> 8;
  const int sA_r  = (tid >> 2) & 63;
  const int sB_r  = tid >> 2;
  const int slot  = tid & 3;
  const int kslot = ((slot ^ ((tid >> 3) & 3)) * 8);   // pre-swizzled source

  auto stageA = [&](int buf, int h, int T) {
    const int gr = bm * 128 + h * 64 + sA_r;
    const int gc = T * 64 + sA_kh * 32 + kslot;
    async16(A + (size_t)gr * (unsigned)ldA + gc,
            &sm[buf * 8192 + sA_kh * 4096 + h * 2048 + (tid & 255) * 8]);
  };
  auto stageB = [&](int buf, int h, int T) {
    const int gr = bn * 256 + h * 128 + sB_r;
    const bf16_t* g = B + (size_t)gr * (unsigned)ldB + T * 64 + kslot;
    bf16_t* l = &sm[16384 + buf * 16384 + h * 4096 + sB_r * 32 + slot * 8];
    async16(g, l);                 // kh = 0
    async16(g + 32, l + 8192);     // kh = 1
  };

  bf16x8 aF[2][2], bF0[2][2], bF1[2][2];
  auto rdA = [&](int buf, int ih) {
#pragma unroll
    for (int q = 0; q < 2; ++q) {
      const int row = wr * 64 + (ih * 2 + q) * 16 + l16;
#pragma unroll
      for (int kh = 0; kh < 2; ++kh)
        aF[q][kh] = *(const bf16x8*)&sm[buf * 8192 + kh * 4096 + row * 32 +
                                        ((quad ^ swq) * 8)];
    }
  };
  auto rdB = [&](bf16x8 (&f)[2][2], int buf, int jh) {
#pragma unroll
    for (int q = 0; q < 2; ++q) {
      const int row = wc * 64 + (jh * 2 + q) * 16 + l16;
#pragma unroll
      for (int kh = 0; kh < 2; ++kh)
        f[q][kh] = *(const bf16x8*)&sm[16384 + buf * 16384 + kh * 8192 +
                                       row * 32 + ((quad ^ swq) * 8)];
    }
  };

  f32x4 acc[4][4] = {};
  auto quadmma = [&](bf16x8 (&bf)[2][2], int io, int jo) {
#pragma unroll
    for (int qi = 0; qi < 2; ++qi)
#pragma unroll
      for (int qj = 0; qj < 2; ++qj)
#pragma unroll
        for (int kh = 0; kh < 2; ++kh)
          acc[io + qi][jo + qj] = __builtin_amdgcn_mfma_f32_16x16x32_bf16(
              aF[qi][kh], bf[qj][kh], acc[io + qi][jo + qj], 0, 0, 0);
  };

  // prologue: tile0 fully + A0,B0 of tile1
  stageA(0, 0, 0); stageB(0, 0, 0); stageA(0, 1, 0); stageB(0, 1, 0);
  if (NT > 1) {
    stageA(1, 0, 1); stageB(1, 0, 1);
    asm volatile("s_waitcnt vmcnt(3)" ::: "memory");
  } else {
    asm volatile("s_waitcnt vmcnt(0)" ::: "memory");
  }
  __builtin_amdgcn_s_barrier();

  for (int T = 0; T < NT; ++T) {
    const int buf = T & 1;
    // ---- p1: quad(0,0)
    __builtin_amdgcn_sched_barrier(0);
    rdA(buf, 0);
    rdB(bF0, buf, 0);
    if (T + 1 < NT) stageA(buf ^ 1, 1, T + 1);
    __builtin_amdgcn_s_barrier();
    __builtin_amdgcn_s_setprio(1);
    quadmma(bF0, 0, 0);
    __builtin_amdgcn_s_setprio(0);
    __builtin_amdgcn_s_barrier();
    // ---- p2: quad(0,1)
    __builtin_amdgcn_sched_barrier(0);
    rdB(bF1, buf, 1);
    if (T + 1 < NT) stageB(buf ^ 1, 1, T + 1);
    __builtin_amdgcn_s_barrier();
    __builtin_amdgcn_s_setprio(1);
    quadmma(bF1, 0, 2);
    __builtin_amdgcn_s_setprio(0);
    __builtin_amdgcn_s_barrier();
    // ---- p3: quad(1,0)
    __builtin_amdgcn_sched_barrier(0);
    rdA(buf, 1);
    if (T + 2 < NT) stageA(buf, 0, T + 2);
    __builtin_amdgcn_s_barrier();
    __builtin_amdgcn_s_setprio(1);
    quadmma(bF0, 2, 0);
    __builtin_amdgcn_s_setprio(0);
    __builtin_amdgcn_s_barrier();
    // ---- p4: quad(1,1) + per-tile vmcnt
    if (T + 2 < NT) stageB(buf, 0, T + 2);
    __builtin_amdgcn_s_barrier();
    __builtin_amdgcn_s_setprio(1);
    quadmma(bF1, 2, 2);
    __builtin_amdgcn_s_setprio(0);
    if (T + 2 < NT)      asm volatile("s_waitcnt vmcnt(3)" ::: "memory");
    else if (T + 1 < NT) asm volatile("s_waitcnt vmcnt(0)" ::: "memory");
    __builtin_amdgcn_s_barrier();
  }

  if (OUT_MODE == 3) {
    // scores epilogue: exp + dropout-mask + per-row sum
    const bool mbf = (*flag != 0);
    float rp[4][4];
#pragma unroll
    for (int i = 0; i < 4; ++i)
#pragma unroll
      for (int r = 0; r < 4; ++r) rp[i][r] = 0.f;
#pragma unroll
    for (int i = 0; i < 4; ++i) {
      const int gr0 = bm * 128 + wr * 64 + i * 16 + quad * 4;
#pragma unroll
      for (int j = 0; j < 4; ++j) {
        const int gc = bn * 256 + wc * 64 + j * 16 + l16;
#pragma unroll
        for (int r = 0; r < 4; ++r) {
          const int grr = gr0 + r;
          float out = 0.f;
          if (gc <= grr) {
            const float e = __expf(acc[i][j][r] * scale);
            const size_t mIdx = (size_t)grr * S_DIM + gc;
            const float mk = mbf ? bf2f(((const unsigned short*)mask)[mIdx])
                                 : ((const float*)mask)[mIdx];
            out = e * mk;
            rp[i][r] += e;
          }
          ((unsigned short*)C)[(size_t)grr * ldC + gc] = f2bf(out);
        }
      }
    }
#pragma unroll
    for (int i = 0; i < 4; ++i) {
      const int gr0 = bm * 128 + wr * 64 + i * 16 + quad * 4;
#pragma unroll
      for (int r = 0; r < 4; ++r) {
        float p = rp[i][r];
        p += __shfl_xor(p, 1); p += __shfl_xor(p, 2);
        p += __shfl_xor(p, 4); p += __shfl_xor(p, 8);
        if (l16 == 0) atomicAdd(&rowsum[gr0 + r], p);
      }
    }
  } else {
    // av epilogue: normalize by softmax denominator, write d_out
    const bool obf = (*flag != 0);
#pragma unroll
    for (int i = 0; i < 4; ++i) {
      const int gr0 = bm * 128 + wr * 64 + i * 16 + quad * 4;
      float inv[4];
#pragma unroll
      for (int r = 0; r < 4; ++r) inv[r] = 1.0f / rowsum[gr0 + r];
#pragma unroll
      for (int j = 0; j < 4; ++j) {
        const int gc = bn * 256 + wc * 64 + j * 16 + l16;
#pragma unroll
        for (int r = 0; r < 4; ++r) {
          const float v = acc[i][j][r] * inv[r];
          const size_t idx = (size_t)(gr0 + r) * ldC + gc;
          if (obf) ((unsigned short*)C)[idx] = f2bf(v);
          else     ((float*)C)[idx] = v;
        }
      }
    }
  }
}

// sc: 272-block causal triangle over 128-row x 256-col tiles.
// NBN(bm) = (bm+2)>>1; prefix P(2u)=u(u+1), P(2u+1)=(u+1)^2 (proven decode).
__global__ __launch_bounds__(512, 2)
void k_gemm_sc8(const bf16_t* __restrict__ A, const bf16_t* __restrict__ B,
                void* __restrict__ C, const int* __restrict__ flag,
                const void* __restrict__ mask, float* __restrict__ rowsum) {
  __shared__ alignas(16) bf16_t sm[49152];
  const int t = blockIdx.x;
  int u = (int)sqrtf((float)t + 0.5f);
  while ((u + 1) * (u + 1) <= t) ++u;
  while (u * u > t) --u;
  int bm, bn;
  if (t >= u * (u + 1)) { bm = 2 * u;     bn = t - u * (u + 1); }
  else                  { bm = 2 * u - 1; bn = t - u * u; }
  gemm8_body<3>(A, B, C, 6144, 6144, S_DIM, bm, bn, 32,
                0.022097086912079608f /* 1/sqrt(2048) */, flag, mask, rowsum, sm);
}

// av: 8x32 = 256 blocks (all CUs, 1 round), kEnd=(bm+1)*128 -> NT=2(bm+1).
// BM=128 means no super-diagonal reads -> k_zerodiag deleted.
__global__ __launch_bounds__(512, 2)
void k_gemm_av8(const bf16_t* __restrict__ A, const bf16_t* __restrict__ B,
                void* __restrict__ C, const int* __restrict__ flag,
                float* __restrict__ rowsum) {
  __shared__ alignas(16) bf16_t sm[49152];
  const int bm = blockIdx.y;
  gemm8_body<2>(A, B, C, S_DIM, S_DIM, D_DIM, bm, blockIdx.x, 2 * (bm + 1),
                1.0f, flag, nullptr, rowsum, sm);
}

// ---------------------------------------------------------------------------
// v-part of qkv [S, 6144] (cols 4096..6143) -> vT[D,S], bf16, 32x32 tiles
__global__ void k_transpose(const unsigned short* __restrict__ src, int ldS,
                            unsigned short* __restrict__ dst) {
  __shared__ unsigned short tile[32][33];
  const int bx = blockIdx.x * 32;
  const int by = blockIdx.y * 32;
  const int tx = threadIdx.x & 31, ty = threadIdx.x >> 5;
  for (int r = ty; r < 32; r += 8)
    tile[r][tx] = src[(size_t)(by + r) * ldS + bx + tx];
  __syncthreads();
  for (int r = ty; r < 32; r += 8)
    dst[(size_t)(bx + r) * S_DIM + by + tx] = tile[tx][r];
}

// ---------------------------------------------------------------------------
extern "C" void kernel_launch(void* const* d_in, const int* in_sizes, int n_in,
                              void* d_out, int out_size, void* d_ws, size_t ws_size,
                              hipStream_t stream) {
  const size_t MB = 1024ull * 1024ull;
  char* w = (char*)d_ws;
  int* flag = (int*)w;
  float* rowsum = (float*)(w + 256);                             // 16 KB
  char* base = w + 64 * 1024;
  unsigned short* xb   = (unsigned short*)(base);                // 16 MB
  unsigned short* wqkv = (unsigned short*)(base + 16 * MB);      // 24 MB (Wq|Wk|Wv)
  unsigned short* qkv  = (unsigned short*)(base + 40 * MB);      // 48 MB [S, 6144]
  unsigned short* vT   = (unsigned short*)(base + 88 * MB);      // 16 MB [D, S]
  // attn (32 MB) aliases xb + first 16MB of wqkv (dead after qkv GEMM)
  unsigned short* attn = (unsigned short*)(base);

  k_init<<<16, 256, 0, stream>>>((const unsigned int*)d_in[0], flag, rowsum);

  k_tobf16<<<(S_DIM * D_DIM / 4 + 255) / 256, 256, 0, stream>>>(
      d_in[0], xb, S_DIM * D_DIM / 4, flag);
  k_tobf16w<<<(3 * D_DIM * D_DIM / 4) / 256, 256, 0, stream>>>(
      d_in[1], d_in[2], d_in[3], wqkv, flag);

  // qkv = x @ [Wq;Wk;Wv]^T : [4096, 6144], 48x32 = 1536 blocks (m97-lite)
  k_gemm_qkv<<<dim3(6144 / 128, S_DIM / 128), dim3(256), 0, stream>>>(
      (const bf16_t*)xb, (const bf16_t*)wqkv, qkv, D_DIM, D_DIM, 6144, D_DIM);

  // vT[D, S] from v-part of qkv
  k_transpose<<<dim3(D_DIM / 32, S_DIM / 32), 256, 0, stream>>>(
      qkv + 4096, 6144, vT);

  // attn_unnorm = exp(q@k^T/sqrt(d)) * mask; 272 causal 128x256 tiles
  k_gemm_sc8<<<dim3(272), dim3(512), 0, stream>>>(
      (const bf16_t*)qkv, (const bf16_t*)(qkv + 2048), (void*)attn,
      flag, d_in[4], rowsum);

  // out = (attn_unnorm @ vT^T) / rowsum; 8x32 = 256 blocks, causal-K
  k_gemm_av8<<<dim3(8, 32), dim3(512), 0, stream>>>(
      (const bf16_t*)attn, (const bf16_t*)vT, d_out, flag, rowsum);
}